// Round 3
// baseline (1107.779 us; speedup 1.0000x reference)
//
#include <hip/hip_runtime.h>
#include <hip/hip_bf16.h>
#include <float.h>

// Problem constants (B,H,W,D,K) = (16,32,32,256,8192)
#define NROWS 16384      // B*H*W
#define DDIM  256
#define KCB   8192
#define ZQ_ELEMS 4194304 // NROWS*DDIM

// ws layout
#define WS_ESQ_OFF  0                         // float[8192]    32 KB
#define WS_ZSQ_OFF  32768                     // float[16384]   64 KB
#define WS_CAND_OFF 98304                     // u64[16384*32]  4 MB
#define WS_SEL_OFF  (98304 + 4194304)         // int[16384]     64 KB
#define WS_LOSS_OFF (98304 + 4194304 + 65536) // double[1]

#define TILE_M 128
#define TILE_N 128
#define TILE_D 32
#define LPAD   132

#define RESCORE_EPS 1e-3f

__device__ __forceinline__ unsigned sortable_bits(float f) {
    unsigned b = __float_as_uint(f);
    return (b & 0x80000000u) ? ~b : (b | 0x80000000u);
}
__device__ __forceinline__ float unsortable_bits(unsigned u) {
    unsigned b = (u & 0x80000000u) ? (u ^ 0x80000000u) : ~u;
    return __uint_as_float(b);
}
__device__ __forceinline__ unsigned long long shfl_xor_u64(unsigned long long v, int m) {
    unsigned lo = __shfl_xor((unsigned)v, m);
    unsigned hi = __shfl_xor((unsigned)(v >> 32), m);
    return ((unsigned long long)hi << 32) | lo;
}

// numpy-pairwise sum of squares per 256-elem row, bit-exact vs np.sum(x**2, -1):
// n=256 -> pairwise(0..127) + pairwise(128..255); each 128-block: 8 sequential
// accumulators r[j] += a[8t+j], combined ((r0+r1)+(r2+r3))+((r4+r5)+(r6+r7)).
// 16-lane group per row: lane = (b<<3)|j; butterfly xor(1,2,4) = block combine
// tree (fp32 add commutative => identical bits), xor(8) = block0+block1.
__global__ __launch_bounds__(256) void sumsq_np_kernel(const float* __restrict__ x,
                                                       float* __restrict__ out,
                                                       int nrows) {
#pragma clang fp contract(off)
    int g = threadIdx.x >> 4;
    int l = threadIdx.x & 15;
    int row = blockIdx.x * 16 + g;
    if (row >= nrows) return;
    int b = l >> 3, j = l & 7;
    const float* a = x + (size_t)row * DDIM + b * 128 + j;
    float v0 = a[0];
    float r = v0 * v0;
    for (int t = 1; t < 16; ++t) {
        float v = a[t * 8];
        float q = v * v;   // contract(off): square rounds before add
        r = r + q;
    }
    r = r + __shfl_xor(r, 1);
    r = r + __shfl_xor(r, 2);
    r = r + __shfl_xor(r, 4);
    r = r + __shfl_xor(r, 8);
    if (l == 0) out[row] = r;
}

// Fused distance filter + per-block top-2 candidates. Block: 128 rows x 512 cols.
// key(n,k) = e_sq[k] - 2*dot(z_n,e_k) (z_sq dropped; filter only, rounding free)
__global__ __launch_bounds__(256, 2) void dist_argmin_kernel(
    const float* __restrict__ z, const float* __restrict__ cb,
    const float* __restrict__ esq, unsigned long long* __restrict__ cand) {
    __shared__ float Zs[TILE_D][LPAD];
    __shared__ float Es[TILE_D][LPAD];

    const int tid = threadIdx.x;
    const int tx = tid & 15;
    const int ty = tid >> 4;
    const int m0 = blockIdx.y * TILE_M;
    const int lm = tid >> 3;
    const int ldv = (tid & 7) * 4;

    unsigned long long bestp[8];
#pragma unroll
    for (int i = 0; i < 8; ++i) bestp[i] = ~0ull;

    for (int ct = 0; ct < 4; ++ct) {
        const int n0 = (blockIdx.x * 4 + ct) * TILE_N;

        float acc[8][8];
#pragma unroll
        for (int i = 0; i < 8; ++i)
#pragma unroll
            for (int j = 0; j < 8; ++j) acc[i][j] = 0.f;

        for (int d0 = 0; d0 < DDIM; d0 += TILE_D) {
#pragma unroll
            for (int p = 0; p < 4; ++p) {
                int m = lm + p * 32;
                float4 v = *(const float4*)(z + (size_t)(m0 + m) * DDIM + d0 + ldv);
                Zs[ldv + 0][m] = v.x; Zs[ldv + 1][m] = v.y;
                Zs[ldv + 2][m] = v.z; Zs[ldv + 3][m] = v.w;
                float4 u = *(const float4*)(cb + (size_t)(n0 + m) * DDIM + d0 + ldv);
                Es[ldv + 0][m] = u.x; Es[ldv + 1][m] = u.y;
                Es[ldv + 2][m] = u.z; Es[ldv + 3][m] = u.w;
            }
            __syncthreads();
#pragma unroll
            for (int d = 0; d < TILE_D; ++d) {
                float zf[8], ef[8];
                *(float4*)&zf[0] = *(const float4*)&Zs[d][ty * 8];
                *(float4*)&zf[4] = *(const float4*)&Zs[d][ty * 8 + 4];
                *(float4*)&ef[0] = *(const float4*)&Es[d][tx * 8];
                *(float4*)&ef[4] = *(const float4*)&Es[d][tx * 8 + 4];
#pragma unroll
                for (int i = 0; i < 8; ++i)
#pragma unroll
                    for (int j = 0; j < 8; ++j)
                        acc[i][j] = fmaf(zf[i], ef[j], acc[i][j]);
            }
            __syncthreads();
        }

#pragma unroll
        for (int i = 0; i < 8; ++i) {
#pragma unroll
            for (int j = 0; j < 8; ++j) {
                int k = n0 + tx * 8 + j;
                float f = esq[k] - 2.0f * acc[i][j];
                unsigned long long pk =
                    ((unsigned long long)sortable_bits(f) << 32) | (unsigned)k;
                if (pk < bestp[i]) bestp[i] = pk;
            }
        }
    }

    // per-row block top-2 across the 16 tx-lanes
#pragma unroll
    for (int i = 0; i < 8; ++i) {
        unsigned long long b1 = bestp[i];
        unsigned long long b2 = ~0ull;
#pragma unroll
        for (int s = 1; s < 16; s <<= 1) {
            unsigned long long o1 = shfl_xor_u64(b1, s);
            unsigned long long o2 = shfl_xor_u64(b2, s);
            unsigned long long n1 = (b1 < o1) ? b1 : o1;
            unsigned long long x  = (b1 < o1) ? o1 : b1;
            unsigned long long y  = (b2 < o2) ? b2 : o2;
            unsigned long long n2 = (x < y) ? x : y;
            b1 = n1; b2 = n2;
        }
        if (tx == 0) {
            int row = m0 + ty * 8 + i;
            cand[(size_t)row * 32 + blockIdx.x * 2 + 0] = b1;
            cand[(size_t)row * 32 + blockIdx.x * 2 + 1] = b2;
        }
    }
}

// rescore near-best candidates with a bit-replica of numpy's fp32 pipeline:
// dist = fp32( fp32(z_sq + e_sq) - 2*chain ), chain = sequential fmaf k=0..255
// (BLAS sgemm microkernel: single accumulator per C elem, ascending K, fma)
__global__ __launch_bounds__(64) void resolve_kernel(
    const float* __restrict__ z, const float* __restrict__ cb,
    const float* __restrict__ zsq, const float* __restrict__ esq,
    const unsigned long long* __restrict__ cand, int* __restrict__ sel,
    float* __restrict__ out) {
#pragma clang fp contract(off)
    int row = blockIdx.x;
    int l = threadIdx.x;
    unsigned long long c = (l < 32) ? cand[(size_t)row * 32 + l] : ~0ull;

    unsigned long long m = c;
#pragma unroll
    for (int s = 32; s; s >>= 1) {
        unsigned long long o = shfl_xor_u64(m, s);
        if (o < m) m = o;
    }
    float bestf = unsortable_bits((unsigned)(m >> 32));
    float myf = unsortable_bits((unsigned)(c >> 32));
    bool active = (l < 32) && (myf <= bestf + RESCORE_EPS);

    float dref = FLT_MAX;
    int k = 0x7FFFFFFF;
    if (active) {
        k = (int)(unsigned)(c & 0xFFFFFFFFull);
        const float* zr = z + (size_t)row * DDIM;
        const float* er = cb + (size_t)k * DDIM;
        float cacc = 0.f;
        for (int d = 0; d < DDIM; ++d)
            cacc = fmaf(zr[d], er[d], cacc);
        float s1 = zsq[row] + esq[k];   // fp32 round (numpy: z_sq + e_sq)
        float two = 2.0f * cacc;        // exact
        dref = s1 - two;                // single fp32 round
    }
    // 64-lane (dist,k) argmin, lowest-k tiebreak == np.argmin
#pragma unroll
    for (int s = 32; s; s >>= 1) {
        float od = __shfl_xor(dref, s);
        int ok = __shfl_xor(k, s);
        if (od < dref || (od == dref && ok < k)) { dref = od; k = ok; }
    }
    if (l == 0) {
        sel[row] = k;
        out[ZQ_ELEMS + row] = (float)k;
    }
}

// gather z_q, write z_q_st, accumulate loss (double for safety)
__global__ __launch_bounds__(64) void gather_kernel(
    const float* __restrict__ z, const float* __restrict__ cb,
    const int* __restrict__ sel, float* __restrict__ out,
    double* __restrict__ loss) {
    int row = blockIdx.x;
    int l = threadIdx.x;
    int k = sel[row];
    float s = 0.f;
#pragma unroll
    for (int t = 0; t < 4; ++t) {
        int d = l + t * 64;
        float e = cb[(size_t)k * DDIM + d];
        float zv = z[(size_t)row * DDIM + d];
        out[(size_t)row * DDIM + d] = zv + (e - zv); // z_q_st == z_q numerically
        float df = zv - e;
        s = fmaf(df, df, s);
    }
#pragma unroll
    for (int m = 32; m; m >>= 1) s += __shfl_xor(s, m);
    if (l == 0) atomicAdd(loss, (double)s);
}

__global__ void final_kernel(const double* __restrict__ loss, float* __restrict__ out) {
    // vq_loss = codebook_loss + 0.25*commitment = 1.25 * mean((z - z_q)^2)
    out[ZQ_ELEMS + NROWS] = (float)(1.25 * loss[0] / (double)ZQ_ELEMS);
}

extern "C" void kernel_launch(void* const* d_in, const int* in_sizes, int n_in,
                              void* d_out, int out_size, void* d_ws, size_t ws_size,
                              hipStream_t stream) {
    const float* z = (const float*)d_in[0];
    const float* cb = (const float*)d_in[1];
    float* out = (float*)d_out;
    char* ws = (char*)d_ws;
    float* esq = (float*)(ws + WS_ESQ_OFF);
    float* zsq = (float*)(ws + WS_ZSQ_OFF);
    unsigned long long* cand = (unsigned long long*)(ws + WS_CAND_OFF);
    int* sel = (int*)(ws + WS_SEL_OFF);
    double* loss = (double*)(ws + WS_LOSS_OFF);

    hipMemsetAsync(loss, 0, sizeof(double), stream);

    sumsq_np_kernel<<<dim3(KCB / 16), 256, 0, stream>>>(cb, esq, KCB);
    sumsq_np_kernel<<<dim3(NROWS / 16), 256, 0, stream>>>(z, zsq, NROWS);
    dist_argmin_kernel<<<dim3(KCB / TILE_N / 4, NROWS / TILE_M), 256, 0, stream>>>(
        z, cb, esq, cand);
    resolve_kernel<<<dim3(NROWS), 64, 0, stream>>>(z, cb, zsq, esq, cand, sel, out);
    gather_kernel<<<dim3(NROWS), 64, 0, stream>>>(z, cb, sel, out, loss);
    final_kernel<<<1, 1, 0, stream>>>(loss, out);
}

// Round 4
// 967.413 us; speedup vs baseline: 1.1451x; 1.1451x over previous
//
#include <hip/hip_runtime.h>
#include <hip/hip_bf16.h>
#include <float.h>

// Problem constants (B,H,W,D,K) = (16,32,32,256,8192)
#define NROWS 16384      // B*H*W
#define DDIM  256
#define KCB   8192
#define ZQ_ELEMS 4194304 // NROWS*DDIM

// ws layout (same footprint class as round 3: ~4.3 MB)
#define WS_ESQ_OFF  0                         // float[8192]    32 KB
#define WS_ZSQ_OFF  32768                     // float[16384]   64 KB
#define WS_CAND_OFF 98304                     // u64[16384*32]  4 MB
#define WS_LOSS_OFF (98304 + 4194304)         // double[1]

// bf16-filter noise is ~1e-3 (2 sigma); 0.02 is a ~20-sigma rescore window
#define RESCORE_EPS 0.02f

// GEMM filter tiling
#define GBK 64
#define APAD 8
#define ASTRIDE (GBK + APAD)   // 72 bf16 = 144 B row stride (16B-aligned)

typedef __attribute__((ext_vector_type(8))) short short8;
typedef __attribute__((ext_vector_type(4))) float floatx4;

__device__ __forceinline__ unsigned sortable_bits(float f) {
    unsigned b = __float_as_uint(f);
    return (b & 0x80000000u) ? ~b : (b | 0x80000000u);
}
__device__ __forceinline__ float unsortable_bits(unsigned u) {
    unsigned b = (u & 0x80000000u) ? (u ^ 0x80000000u) : ~u;
    return __uint_as_float(b);
}
__device__ __forceinline__ unsigned long long shfl_xor_u64(unsigned long long v, int m) {
    unsigned lo = __shfl_xor((unsigned)v, m);
    unsigned hi = __shfl_xor((unsigned)(v >> 32), m);
    return ((unsigned long long)hi << 32) | lo;
}
__device__ __forceinline__ unsigned short bf16_rn(float f) {
    unsigned u = __float_as_uint(f);
    return (unsigned short)((u + 0x7FFFu + ((u >> 16) & 1u)) >> 16);
}
__device__ __forceinline__ void top2_ins(unsigned long long& b1, unsigned long long& b2,
                                         unsigned long long p) {
    if (p < b1) { b2 = b1; b1 = p; }
    else if (p < b2) b2 = p;
}

// numpy-pairwise sum of squares, bit-exact vs np.sum(x**2,-1) (proven round 3).
// Fused: rows [0,KCB) -> esq from cb; rows [KCB,KCB+NROWS) -> zsq from z.
__global__ __launch_bounds__(256) void sumsq_np_kernel(const float* __restrict__ z,
                                                       const float* __restrict__ cb,
                                                       float* __restrict__ esq,
                                                       float* __restrict__ zsq) {
#pragma clang fp contract(off)
    int g = threadIdx.x >> 4;
    int l = threadIdx.x & 15;
    int row = blockIdx.x * 16 + g;
    const float* x;
    float* o;
    if (row < KCB) { x = cb + (size_t)row * DDIM; o = esq + row; }
    else { x = z + (size_t)(row - KCB) * DDIM; o = zsq + (row - KCB); }
    int b = l >> 3, j = l & 7;
    const float* a = x + b * 128 + j;
    float v0 = a[0];
    float r = v0 * v0;
    for (int t = 1; t < 16; ++t) {
        float v = a[t * 8];
        float q = v * v;
        r = r + q;
    }
    r = r + __shfl_xor(r, 1);
    r = r + __shfl_xor(r, 2);
    r = r + __shfl_xor(r, 4);
    r = r + __shfl_xor(r, 8);
    if (l == 0) *o = r;
}

// bf16 MFMA distance filter. Block: 128 z-rows x 4 col-tiles of 128 (512 cols).
// Converts fp32->bf16 (RNE) during LDS staging; key = esq[k] - 2*dot_bf16.
// Keeps per-row top-2 over the block's 512 cols (register butterfly + LDS state).
__global__ __launch_bounds__(256, 3) void gemm_filter_kernel(
    const float* __restrict__ z, const float* __restrict__ cb,
    const float* __restrict__ esq, unsigned long long* __restrict__ cand) {
    __shared__ unsigned short As[128 * ASTRIDE];
    __shared__ unsigned short Bs[128 * ASTRIDE];
    __shared__ unsigned long long st[128][2][2];

    const int tid = threadIdx.x;
    const int wave = tid >> 6;
    const int lane = tid & 63;
    const int mh = wave >> 1;   // row half (64 rows)
    const int nh = wave & 1;    // col half (64 cols)
    const int q = lane >> 4;
    const int c = lane & 15;
    const int m0 = blockIdx.y * 128;
    const int sr = tid >> 4;    // staging row 0..15
    const int sc = tid & 15;    // staging float4 index within 64-float chunk

    for (int ct = 0; ct < 4; ++ct) {
        const int n0 = (blockIdx.x * 4 + ct) * 128;

        floatx4 acc[4][4];
#pragma unroll
        for (int f = 0; f < 4; ++f)
#pragma unroll
            for (int nf = 0; nf < 4; ++nf) acc[f][nf] = (floatx4){0.f, 0.f, 0.f, 0.f};

        float ekeys[4];
#pragma unroll
        for (int nf = 0; nf < 4; ++nf) ekeys[nf] = esq[n0 + nh * 64 + nf * 16 + c];

        for (int kt = 0; kt < 4; ++kt) {
            const int kb = kt * GBK;
            __syncthreads();  // previous readers done before restage
#pragma unroll
            for (int i = 0; i < 8; ++i) {
                int r = sr + i * 16;
                float4 v = *(const float4*)(z + (size_t)(m0 + r) * DDIM + kb + sc * 4);
                ushort4 w;
                w.x = bf16_rn(v.x); w.y = bf16_rn(v.y);
                w.z = bf16_rn(v.z); w.w = bf16_rn(v.w);
                *(ushort4*)&As[r * ASTRIDE + sc * 4] = w;
                float4 u = *(const float4*)(cb + (size_t)(n0 + r) * DDIM + kb + sc * 4);
                ushort4 w2;
                w2.x = bf16_rn(u.x); w2.y = bf16_rn(u.y);
                w2.z = bf16_rn(u.z); w2.w = bf16_rn(u.w);
                *(ushort4*)&Bs[r * ASTRIDE + sc * 4] = w2;
            }
            __syncthreads();
#pragma unroll
            for (int ks = 0; ks < 2; ++ks) {
                const int koff = ks * 32 + q * 8;
                short8 af[4], bf[4];
#pragma unroll
                for (int f = 0; f < 4; ++f)
                    af[f] = *(const short8*)&As[(mh * 64 + f * 16 + c) * ASTRIDE + koff];
#pragma unroll
                for (int nf = 0; nf < 4; ++nf)
                    bf[nf] = *(const short8*)&Bs[(nh * 64 + nf * 16 + c) * ASTRIDE + koff];
#pragma unroll
                for (int f = 0; f < 4; ++f)
#pragma unroll
                    for (int nf = 0; nf < 4; ++nf)
                        acc[f][nf] = __builtin_amdgcn_mfma_f32_16x16x32_bf16(
                            af[f], bf[nf], acc[f][nf], 0, 0, 0);
            }
        }

        // epilogue: per-row top-2 over this ct's 64 cols (per nh), fold into LDS state
#pragma unroll
        for (int f = 0; f < 4; ++f) {
#pragma unroll
            for (int r = 0; r < 4; ++r) {
                unsigned long long b1 = ~0ull, b2 = ~0ull;
#pragma unroll
                for (int nf = 0; nf < 4; ++nf) {
                    float key = fmaf(-2.0f, acc[f][nf][r], ekeys[nf]);
                    int k = n0 + nh * 64 + nf * 16 + c;
                    unsigned long long p =
                        ((unsigned long long)sortable_bits(key) << 32) | (unsigned)k;
                    top2_ins(b1, b2, p);
                }
#pragma unroll
                for (int s = 1; s < 16; s <<= 1) {
                    unsigned long long o1 = shfl_xor_u64(b1, s);
                    unsigned long long o2 = shfl_xor_u64(b2, s);
                    unsigned long long n1 = (b1 < o1) ? b1 : o1;
                    unsigned long long x = (b1 < o1) ? o1 : b1;
                    unsigned long long y = (o2 < b2) ? o2 : b2;
                    b1 = n1;
                    b2 = (x < y) ? x : y;
                }
                if (c == 0) {
                    int lrow = mh * 64 + f * 16 + q * 4 + r;
                    if (ct == 0) {
                        st[lrow][nh][0] = b1;
                        st[lrow][nh][1] = b2;
                    } else {
                        unsigned long long s1 = st[lrow][nh][0];
                        unsigned long long s2 = st[lrow][nh][1];
                        unsigned long long m1 = (s1 < b1) ? s1 : b1;
                        unsigned long long m2 =
                            (s1 < b1) ? ((s2 < b1) ? s2 : b1) : ((b2 < s1) ? b2 : s1);
                        st[lrow][nh][0] = m1;
                        st[lrow][nh][1] = m2;
                    }
                }
            }
        }
    }

    __syncthreads();
    if (tid < 128) {
        unsigned long long a0 = st[tid][0][0], a1 = st[tid][0][1];
        unsigned long long b0 = st[tid][1][0], b1 = st[tid][1][1];
        unsigned long long m1 = (a0 < b0) ? a0 : b0;
        unsigned long long m2 = (a0 < b0) ? ((a1 < b0) ? a1 : b0) : ((b1 < a0) ? b1 : a0);
        size_t row = (size_t)(m0 + tid);
        cand[row * 32 + blockIdx.x * 2 + 0] = m1;
        cand[row * 32 + blockIdx.x * 2 + 1] = m2;
    }
}

// rescore near-best candidates with the numpy-replica fp32 pipeline (proven
// round 3), then fused gather + loss. One wave per row.
__global__ __launch_bounds__(64) void resolve_gather_kernel(
    const float* __restrict__ z, const float* __restrict__ cb,
    const float* __restrict__ zsq, const float* __restrict__ esq,
    const unsigned long long* __restrict__ cand, float* __restrict__ out,
    double* __restrict__ loss) {
#pragma clang fp contract(off)
    int row = blockIdx.x;
    int l = threadIdx.x;
    unsigned long long c = (l < 32) ? cand[(size_t)row * 32 + l] : ~0ull;

    unsigned long long m = c;
#pragma unroll
    for (int s = 32; s; s >>= 1) {
        unsigned long long o = shfl_xor_u64(m, s);
        if (o < m) m = o;
    }
    float bestf = unsortable_bits((unsigned)(m >> 32));
    float myf = unsortable_bits((unsigned)(c >> 32));
    bool active = (l < 32) && (myf <= bestf + RESCORE_EPS);

    float dref = FLT_MAX;
    int k = 0x7FFFFFFF;
    if (active) {
        k = (int)(unsigned)(c & 0xFFFFFFFFull);
        const float* zr = z + (size_t)row * DDIM;
        const float* er = cb + (size_t)k * DDIM;
        float cacc = 0.f;
        for (int d = 0; d < DDIM; ++d)
            cacc = fmaf(zr[d], er[d], cacc);   // BLAS-style sequential-K fma chain
        float s1 = zsq[row] + esq[k];          // numpy: z_sq + e_sq (fp32 round)
        float two = 2.0f * cacc;               // exact
        dref = s1 - two;                       // single fp32 round
    }
#pragma unroll
    for (int s = 32; s; s >>= 1) {
        float od = __shfl_xor(dref, s);
        int ok = __shfl_xor(k, s);
        if (od < dref || (od == dref && ok < k)) { dref = od; k = ok; }
    }
    // k now uniform across the wave
    if (l == 0) out[ZQ_ELEMS + row] = (float)k;

    float s = 0.f;
#pragma unroll
    for (int t = 0; t < 4; ++t) {
        int d = l + t * 64;
        float e = cb[(size_t)k * DDIM + d];
        float zv = z[(size_t)row * DDIM + d];
        out[(size_t)row * DDIM + d] = zv + (e - zv); // z_q_st == z_q numerically
        float df = zv - e;
        s = fmaf(df, df, s);
    }
#pragma unroll
    for (int mm = 32; mm; mm >>= 1) s += __shfl_xor(s, mm);
    if (l == 0) atomicAdd(loss, (double)s);
}

__global__ void final_kernel(const double* __restrict__ loss, float* __restrict__ out) {
    // vq_loss = codebook_loss + 0.25*commitment = 1.25 * mean((z - z_q)^2)
    out[ZQ_ELEMS + NROWS] = (float)(1.25 * loss[0] / (double)ZQ_ELEMS);
}

extern "C" void kernel_launch(void* const* d_in, const int* in_sizes, int n_in,
                              void* d_out, int out_size, void* d_ws, size_t ws_size,
                              hipStream_t stream) {
    const float* z = (const float*)d_in[0];
    const float* cb = (const float*)d_in[1];
    float* out = (float*)d_out;
    char* ws = (char*)d_ws;
    float* esq = (float*)(ws + WS_ESQ_OFF);
    float* zsq = (float*)(ws + WS_ZSQ_OFF);
    unsigned long long* cand = (unsigned long long*)(ws + WS_CAND_OFF);
    double* loss = (double*)(ws + WS_LOSS_OFF);

    hipMemsetAsync(loss, 0, sizeof(double), stream);

    sumsq_np_kernel<<<dim3((KCB + NROWS) / 16), 256, 0, stream>>>(z, cb, esq, zsq);
    gemm_filter_kernel<<<dim3(16, 128), 256, 0, stream>>>(z, cb, esq, cand);
    resolve_gather_kernel<<<dim3(NROWS), 64, 0, stream>>>(z, cb, zsq, esq, cand, out, loss);
    final_kernel<<<1, 1, 0, stream>>>(loss, out);
}

// Round 5
// 243.138 us; speedup vs baseline: 4.5562x; 3.9789x over previous
//
#include <hip/hip_runtime.h>
#include <hip/hip_bf16.h>
#include <float.h>

// Problem constants (B,H,W,D,K) = (16,32,32,256,8192)
#define NROWS 16384
#define DDIM  256
#define KCB   8192
#define ZQ_ELEMS 4194304

// ws layout (~2.2 MB; <= round-3's proven 4.3 MB)
#define WS_ESQ_OFF   0                      // float[8192]
#define WS_ZSQ_OFF   32768                  // float[16384]
#define WS_CAND_OFF  98304                  // u32[16384*32] = 2 MB
#define WS_PART_OFF  (98304 + 2097152)      // float[4096]
// bf16 copies of z/cb live in d_out scratch (overwritten later by outputs)

#define QWINDOW 410   // rescore window: 0.025 in 1/16384 fixed-point quanta

typedef __attribute__((ext_vector_type(8))) short short8;
typedef __attribute__((ext_vector_type(4))) float floatx4;

__device__ __forceinline__ unsigned short bf16_rn(float f) {
    unsigned u = __float_as_uint(f);
    return (unsigned short)((u + 0x7FFFu + ((u >> 16) & 1u)) >> 16);
}

// async global->LDS DMA, 16 B per lane; LDS dest = wave-uniform base + lane*16
__device__ __forceinline__ void gload_lds16(const void* g, void* l) {
    __builtin_amdgcn_global_load_lds(
        (const __attribute__((address_space(1))) void*)(uintptr_t)g,
        (__attribute__((address_space(3))) void*)(unsigned)(uintptr_t)l, 16, 0, 0);
}

// ---------- prep: bf16 convert + numpy-pairwise sumsq (bit-exact, proven r3) ----
// 4 lanes per 256-elem row: lane sub = b*2+jq holds accumulators j=jq*4..+3 of
// 128-block b; in-lane (r0+r1)+(r2+r3) then xor(1)=jq pair, xor(2)=block pair
// reproduces numpy's ((j0+j1)+(j2+j3))+((j4+j5)+(j6+j7)), blk0+blk1 tree.
__global__ __launch_bounds__(256) void prep_kernel(
    const float* __restrict__ z, const float* __restrict__ cb,
    unsigned short* __restrict__ z16, unsigned short* __restrict__ cb16,
    float* __restrict__ esq, float* __restrict__ zsq) {
#pragma clang fp contract(off)
    int tid = threadIdx.x;
    int rowb = tid >> 2, sub = tid & 3;
    int b = sub >> 1, jq = sub & 1;
    int row = blockIdx.x * 64 + rowb;
    const float* src; unsigned short* dst; float* o;
    if (row < KCB) { src = cb + (size_t)row * DDIM; dst = cb16 + (size_t)row * DDIM; o = esq + row; }
    else { int r = row - KCB; src = z + (size_t)r * DDIM; dst = z16 + (size_t)r * DDIM; o = zsq + r; }
    float r0 = 0.f, r1 = 0.f, r2 = 0.f, r3 = 0.f;
    for (int t = 0; t < 16; ++t) {
        int off = b * 128 + t * 8 + jq * 4;
        float4 v = *(const float4*)(src + off);
        float q0 = v.x * v.x, q1 = v.y * v.y, q2 = v.z * v.z, q3 = v.w * v.w;
        r0 = r0 + q0; r1 = r1 + q1; r2 = r2 + q2; r3 = r3 + q3;
        ushort4 w;
        w.x = bf16_rn(v.x); w.y = bf16_rn(v.y); w.z = bf16_rn(v.z); w.w = bf16_rn(v.w);
        *(ushort4*)(dst + off) = w;
    }
    float s = (r0 + r1) + (r2 + r3);
    s = s + __shfl_xor(s, 1);   // jq pair
    s = s + __shfl_xor(s, 2);   // block pair
    if (sub == 0) *o = s;
}

// ---------- bf16 MFMA filter: block = 64 z-rows x 512 cols ----------
// A(z) 64x256 staged once via global_load_lds (XOR-swizzled); cb in 128x64
// double-buffered chunks. kt-outer: acc[4ct][4f][2nf] persists, A-frags read
// once per kt. Epilogue: u32 fixed-point packed keys, top-2 per row per block.
__global__ __launch_bounds__(256, 2) void gemm_filter_kernel(
    const unsigned short* __restrict__ z16, const unsigned short* __restrict__ cb16,
    const float* __restrict__ esq, unsigned* __restrict__ cand) {
    __shared__ unsigned short As[64 * 256];     // 32 KB
    __shared__ unsigned short Bs[2][128 * 64];  // 2 x 16 KB
    __shared__ unsigned st[64][4][2];           // 2 KB cross-wave top-2 merge

    const int tid = threadIdx.x;
    const int w = tid >> 6, lane = tid & 63;
    const int c = lane & 15, q = lane >> 4;
    const int m0 = blockIdx.y * 64;
    const int nbase = blockIdx.x * 512;

    // prologue: A tile + B chunk 0
#pragma unroll
    for (int p = 0; p < 8; ++p) {
        int s = (w * 8 + p) * 64 + lane;
        int row = s >> 5, jp = s & 31;
        int j = (jp & 24) | ((jp & 7) ^ (row & 7));   // source-addr XOR swizzle
        gload_lds16(z16 + (size_t)(m0 + row) * 256 + j * 8,
                    (char*)As + (w * 8 + p) * 1024);
    }
#pragma unroll
    for (int p = 0; p < 4; ++p) {
        int s = (w * 4 + p) * 64 + lane;
        int col = s >> 3, jp = s & 7;
        int j = jp ^ (col & 7);
        gload_lds16(cb16 + (size_t)(nbase + col) * 256 + j * 8,
                    (char*)Bs[0] + (w * 4 + p) * 1024);
    }
    __syncthreads();

    floatx4 acc[4][4][2];   // [ct][f][nf]
#pragma unroll
    for (int ct = 0; ct < 4; ++ct)
#pragma unroll
        for (int f = 0; f < 4; ++f)
#pragma unroll
            for (int nf = 0; nf < 2; ++nf) acc[ct][f][nf] = (floatx4){0.f, 0.f, 0.f, 0.f};

    short8 af[4][2];   // [f][ks] for current kt

#pragma unroll
    for (int s5 = 0; s5 < 16; ++s5) {
        const int kt = s5 >> 2, ct = s5 & 3, cur = s5 & 1;
        if (s5 < 15) {   // prefetch next cb chunk into other buffer
            const int nkt = (s5 + 1) >> 2, nct = (s5 + 1) & 3;
#pragma unroll
            for (int p = 0; p < 4; ++p) {
                int s = (w * 4 + p) * 64 + lane;
                int col = s >> 3, jp = s & 7;
                int j = jp ^ (col & 7);
                gload_lds16(cb16 + (size_t)(nbase + nct * 128 + col) * 256 + nkt * 64 + j * 8,
                            (char*)Bs[cur ^ 1] + (w * 4 + p) * 1024);
            }
        }
        if (ct == 0) {   // A-frags for this kt (reused across 4 ct)
#pragma unroll
            for (int f = 0; f < 4; ++f)
#pragma unroll
                for (int ks = 0; ks < 2; ++ks) {
                    int row = f * 16 + c;
                    af[f][ks] = *(const short8*)((const char*)As + row * 512 +
                                 (kt * 8 + (((ks * 4 + q)) ^ (row & 7))) * 16);
                }
        }
        short8 bf[2][2];
#pragma unroll
        for (int nf = 0; nf < 2; ++nf)
#pragma unroll
            for (int ks = 0; ks < 2; ++ks) {
                int col = w * 32 + nf * 16 + c;
                bf[nf][ks] = *(const short8*)((const char*)Bs[cur] + col * 128 +
                              (((ks * 4 + q) ^ (col & 7))) * 16);
            }
#pragma unroll
        for (int f = 0; f < 4; ++f)
#pragma unroll
            for (int nf = 0; nf < 2; ++nf) {
                acc[ct][f][nf] = __builtin_amdgcn_mfma_f32_16x16x32_bf16(
                    af[f][0], bf[nf][0], acc[ct][f][nf], 0, 0, 0);
                acc[ct][f][nf] = __builtin_amdgcn_mfma_f32_16x16x32_bf16(
                    af[f][1], bf[nf][1], acc[ct][f][nf], 0, 0, 0);
            }
        __syncthreads();   // buf cur consumed; next chunk's DMA drained here
    }

    // ---- epilogue (once per block): fixed-point pack + top-2 ----
    float ekf[4][2]; unsigned kb[4][2];
#pragma unroll
    for (int ct = 0; ct < 4; ++ct)
#pragma unroll
        for (int nf = 0; nf < 2; ++nf) {
            int col = nbase + ct * 128 + w * 32 + nf * 16 + c;
            ekf[ct][nf] = (esq[col] + 8.0f) * 16384.0f;   // key+8 in quanta
            kb[ct][nf] = (unsigned)col;
        }
    unsigned b1[4][4], b2[4][4];
#pragma unroll
    for (int f = 0; f < 4; ++f)
#pragma unroll
        for (int r = 0; r < 4; ++r) { b1[f][r] = 0xFFFFFFFFu; b2[f][r] = 0xFFFFFFFFu; }
#pragma unroll
    for (int f = 0; f < 4; ++f)
#pragma unroll
        for (int r = 0; r < 4; ++r)
#pragma unroll
            for (int ct = 0; ct < 4; ++ct)
#pragma unroll
                for (int nf = 0; nf < 2; ++nf) {
                    float fx = fmaf(-32768.0f, acc[ct][f][nf][r], ekf[ct][nf]);
                    unsigned p = ((unsigned)fx << 13) | kb[ct][nf];
                    unsigned t = min(p, b2[f][r]);
                    b2[f][r] = max(t, b1[f][r]);   // med3(p, b1, b2)
                    b1[f][r] = min(b1[f][r], p);
                }
#pragma unroll
    for (int f = 0; f < 4; ++f)
#pragma unroll
        for (int r = 0; r < 4; ++r) {
            unsigned x1 = b1[f][r], x2 = b2[f][r];
#pragma unroll
            for (int sft = 1; sft < 16; sft <<= 1) {
                unsigned o1 = __shfl_xor(x1, sft);
                unsigned o2 = __shfl_xor(x2, sft);
                unsigned mx = max(x1, o1);
                x1 = min(x1, o1);
                x2 = min(min(mx, x2), o2);
            }
            if (c == 0) {
                st[f * 16 + q * 4 + r][w][0] = x1;
                st[f * 16 + q * 4 + r][w][1] = x2;
            }
        }
    __syncthreads();
    if (tid < 64) {
        unsigned a1 = st[tid][0][0], a2 = st[tid][0][1];
#pragma unroll
        for (int ww = 1; ww < 4; ++ww) {
            unsigned p1 = st[tid][ww][0], p2 = st[tid][ww][1];
            unsigned mx = max(a1, p1);
            a1 = min(a1, p1);
            a2 = min(min(mx, a2), p2);
        }
        cand[(size_t)(m0 + tid) * 32 + blockIdx.x * 2 + 0] = a1;
        cand[(size_t)(m0 + tid) * 32 + blockIdx.x * 2 + 1] = a2;
    }
}

// ---------- resolve (numpy-replica fp32 rescore, proven r3/r4) + gather ------
__global__ __launch_bounds__(256) void resolve_gather_kernel(
    const float* __restrict__ z, const float* __restrict__ cb,
    const float* __restrict__ zsq, const float* __restrict__ esq,
    const unsigned* __restrict__ cand, float* __restrict__ out,
    float* __restrict__ partials) {
#pragma clang fp contract(off)
    __shared__ float wls[4];
    int w = threadIdx.x >> 6, l = threadIdx.x & 63;
    int row = blockIdx.x * 4 + w;
    unsigned p = (l < 32) ? cand[(size_t)row * 32 + l] : 0xFFFFFFFFu;
    unsigned m = p;
#pragma unroll
    for (int s = 32; s; s >>= 1) m = min(m, __shfl_xor(m, s));
    bool active = (l < 32) && ((p >> 13) <= (m >> 13) + QWINDOW);
    float dref = FLT_MAX; int k = 0x7FFFFFFF;
    if (active) {
        k = (int)(p & 8191u);
        const float* zr = z + (size_t)row * DDIM;
        const float* er = cb + (size_t)k * DDIM;
        float cacc = 0.f;
        for (int d = 0; d < DDIM; ++d)
            cacc = fmaf(zr[d], er[d], cacc);   // BLAS-style sequential-K fma chain
        float s1 = zsq[row] + esq[k];          // numpy: z_sq + e_sq (fp32 round)
        float two = 2.0f * cacc;               // exact
        dref = s1 - two;                       // single fp32 round
    }
#pragma unroll
    for (int s = 32; s; s >>= 1) {
        float od = __shfl_xor(dref, s);
        int ok = __shfl_xor(k, s);
        if (od < dref || (od == dref && ok < k)) { dref = od; k = ok; }
    }
    if (l == 0) out[ZQ_ELEMS + row] = (float)k;
    float ls = 0.f;
#pragma unroll
    for (int t = 0; t < 4; ++t) {
        int d = l + t * 64;
        float e = cb[(size_t)k * DDIM + d];
        float zv = z[(size_t)row * DDIM + d];
        out[(size_t)row * DDIM + d] = zv + (e - zv);  // z_q_st == z_q numerically
        float df = zv - e;
        ls = fmaf(df, df, ls);
    }
#pragma unroll
    for (int s = 32; s; s >>= 1) ls += __shfl_xor(ls, s);
    if (l == 0) wls[w] = ls;
    __syncthreads();
    if (threadIdx.x == 0)
        partials[blockIdx.x] = (wls[0] + wls[1]) + (wls[2] + wls[3]);
}

__global__ __launch_bounds__(256) void final_kernel(const float* __restrict__ partials,
                                                    float* __restrict__ out) {
    __shared__ double wd[4];
    int w = threadIdx.x >> 6, l = threadIdx.x & 63;
    double s = 0.0;
#pragma unroll
    for (int j = 0; j < 16; ++j) s += (double)partials[threadIdx.x + j * 256];
#pragma unroll
    for (int sh = 32; sh; sh >>= 1) s += __shfl_xor(s, sh);
    if (l == 0) wd[w] = s;
    __syncthreads();
    if (threadIdx.x == 0)
        out[ZQ_ELEMS + NROWS] =
            (float)(1.25 * ((wd[0] + wd[1]) + (wd[2] + wd[3])) / (double)ZQ_ELEMS);
}

extern "C" void kernel_launch(void* const* d_in, const int* in_sizes, int n_in,
                              void* d_out, int out_size, void* d_ws, size_t ws_size,
                              hipStream_t stream) {
    const float* z = (const float*)d_in[0];
    const float* cb = (const float*)d_in[1];
    float* out = (float*)d_out;
    char* ws = (char*)d_ws;
    float* esq = (float*)(ws + WS_ESQ_OFF);
    float* zsq = (float*)(ws + WS_ZSQ_OFF);
    unsigned* cand = (unsigned*)(ws + WS_CAND_OFF);
    float* partials = (float*)(ws + WS_PART_OFF);
    // bf16 scratch inside d_out (12 MB < 16.8 MB); overwritten by outputs later
    unsigned short* z16 = (unsigned short*)d_out;
    unsigned short* cb16 = z16 + (size_t)NROWS * DDIM;

    prep_kernel<<<dim3((KCB + NROWS) / 64), 256, 0, stream>>>(z, cb, z16, cb16, esq, zsq);
    gemm_filter_kernel<<<dim3(16, NROWS / 64), 256, 0, stream>>>(z16, cb16, esq, cand);
    resolve_gather_kernel<<<dim3(NROWS / 4), 256, 0, stream>>>(z, cb, zsq, esq, cand, out, partials);
    final_kernel<<<1, 256, 0, stream>>>(partials, out);
}